// Round 6
// baseline (303.235 us; speedup 1.0000x reference)
//
#include <hip/hip_runtime.h>
#include <math.h>

namespace {
constexpr int N = 8, C = 48, H = 96, W = 72;
constexpr int HW = H * W;        // 6912 = 108*64
constexpr int P = N * HW;        // 55296
constexpr float BN_EPS = 1e-5f;

// ws layout (float offsets)
constexpr int WS_WCAT = 0;                   // wcat[c][t][16]: 0..3 tm, 4..5 tr, 6..14 mk
constexpr int WCAT_SZ = C * 9 * 16;          // 6912
constexpr int WS_DWO  = WS_WCAT + WCAT_SZ;   // dwO[k][o][c], c contiguous
constexpr int DWO_SZ  = 9 * C * C;           // 20736
constexpr int WS_SC   = WS_DWO + DWO_SZ;     // bn scale[48]
constexpr int WS_BI   = WS_SC + C;           // bn bias2[48]
}

// ---------------------------------------------------------------------------
// Weight re-layout + BN fold.
// ---------------------------------------------------------------------------
__global__ void prep_kernel(const float* __restrict__ tm_w, const float* __restrict__ tr_w,
                            const float* __restrict__ mk_w, const float* __restrict__ dw,
                            const float* __restrict__ gamma, const float* __restrict__ beta,
                            const float* __restrict__ rmean, const float* __restrict__ rvar,
                            float* __restrict__ ws)
{
    int tid = blockIdx.x * blockDim.x + threadIdx.x;

    if (tid < WCAT_SZ) {
        int o  = tid & 15;
        int ct = tid >> 4;         // c*9 + t
        int c  = ct / 9;
        int t  = ct - c * 9;
        float v = 0.f;
        if (o < 4)       v = tm_w[(o * C + c) * 9 + t];
        else if (o < 6)  v = tr_w[((o - 4) * C + c) * 9 + t];
        else if (o < 15) v = mk_w[((o - 6) * C + c) * 9 + t];
        ws[WS_WCAT + tid] = v;
    }
    if (tid < DWO_SZ) {
        int c = tid % C;
        int r = tid / C;           // k*C + o
        int o = r % C;
        int k = r / C;
        ws[WS_DWO + tid] = dw[(o * C + c) * 9 + k];
    }
    if (tid < C) {
        float sc = gamma[tid] * rsqrtf(rvar[tid] + BN_EPS);
        ws[WS_SC + tid] = sc;
        ws[WS_BI + tid] = beta[tid] - rmean[tid] * sc;
    }
}

// ---------------------------------------------------------------------------
// Fused kernel. Block = 8 waves over the SAME 64 pixels.
// conv phase : wave wv computes 6 input channels (wave-uniform weights).
// deform     : per k-tap, wave wv SAMPLES its 6 input channels into LDS
//              (double-buffered), then ALL waves accumulate — wave wv owns
//              OUTPUT channels 6wv..6wv+5 (acc[6]/thread, no spills,
//              no epilogue reduce).
// XCD swizzle: blockIdx&7 = batch n, so each XCD's L2 holds one batch.
// ---------------------------------------------------------------------------
__global__ __launch_bounds__(512, 6) void fused_kernel(
    const float* __restrict__ x,
    const float* __restrict__ tm_b, const float* __restrict__ tr_b,
    const float* __restrict__ mk_b,
    const float* __restrict__ ws,
    float* __restrict__ out)
{
    __shared__ float offs[9][3][64];      // 6.9 KB: oy/ox/mk per k-tap
    __shared__ float pool[8 * 15 * 64];   // 30 KB: conv red [8][15][64], then smp [2][48][64]

    int lane = threadIdx.x & 63;
    int wv   = __builtin_amdgcn_readfirstlane(threadIdx.x >> 6);  // 0..7, SGPR

    int b    = blockIdx.x;
    int n    = b & 7;                  // XCD-aligned batch
    int tile = b >> 3;                 // 0..107
    int hw   = tile * 64 + lane;
    int h    = hw / W;
    int w    = hw - h * W;

    const float* xn = x + (size_t)n * C * HW;
    const int c_lo = wv * 6;           // this wave's input-channel slice
    const int o_lo = wv * 6;           // this wave's output-channel slice

    // ================= conv phase: 15-channel 3x3 conv =================
    float cacc[15];
#pragma unroll
    for (int o = 0; o < 15; ++o) cacc[o] = 0.f;

    const float* wcat = ws + WS_WCAT;

#pragma unroll
    for (int cc = 0; cc < 6; ++cc) {
        int c = c_lo + cc;                        // wave-uniform
        const float* xc = xn + c * HW;
        float tap[9];
#pragma unroll
        for (int dy = -1; dy <= 1; ++dy) {
            int hh = h + dy;
            bool vy = (unsigned)hh < (unsigned)H;
#pragma unroll
            for (int dx = -1; dx <= 1; ++dx) {
                int ww = w + dx;
                bool v = vy && ((unsigned)ww < (unsigned)W);
                tap[(dy + 1) * 3 + (dx + 1)] = v ? xc[hh * W + ww] : 0.f;
            }
        }
#pragma unroll
        for (int t = 0; t < 9; ++t) {
            const float* wp = wcat + (c * 9 + t) * 16;   // SGPR base
            float tv = tap[t];
#pragma unroll
            for (int o = 0; o < 15; ++o) cacc[o] = fmaf(tv, wp[o], cacc[o]);
        }
    }

    // cross-wave reduce via pool[8][15][64]
#pragma unroll
    for (int o = 0; o < 15; ++o) pool[(wv * 15 + o) * 64 + lane] = cacc[o];
    __syncthreads();

    float s15[15];
#pragma unroll
    for (int o = 0; o < 15; ++o) {
        float v = pool[o * 64 + lane];
#pragma unroll
        for (int i = 1; i < 8; ++i) v += pool[(i * 15 + o) * 64 + lane];
        s15[o] = v;
    }

    float t0 = s15[0] + tm_b[0], t1 = s15[1] + tm_b[1];
    float t2 = s15[2] + tm_b[2], t3 = s15[3] + tm_b[3];
    float r0 = s15[4] + tr_b[0], r1 = s15[5] + tr_b[1];

    for (int k = wv; k < 9; k += 8) {             // wave 0 does k=0,8
        float ry = (float)(k / 3) - 1.f;
        float rx = (float)(k % 3) - 1.f;
        offs[k][0][lane] = fmaf(t0, ry, fmaf(t1, rx, r0)) - ry;
        offs[k][1][lane] = fmaf(t2, ry, fmaf(t3, rx, r1)) - rx;
        offs[k][2][lane] = s15[6 + k] + mk_b[k];
    }
    __syncthreads();   // also protects pool reuse (red -> smp)

    // ================= deform phase =================
    // smp buffers live in pool: [2][48][64]
    float* smp0 = pool;
    float* smp1 = pool + 48 * 64;

    // sample this wave's 6 input channels for tap k -> sv[6]
    auto sample_tap = [&](int k, float sv[6]) {
        float o_y = offs[k][0][lane];
        float o_x = offs[k][1][lane];
        float m   = offs[k][2][lane];

        float py = (float)(h + k / 3 - 1) + o_y;
        float px = (float)(w + k % 3 - 1) + o_x;

        float y0f = floorf(py), x0f = floorf(px);
        float wy = py - y0f, wx = px - x0f;
        int y0 = (int)y0f, x0 = (int)x0f;
        int y1 = y0 + 1,  x1 = x0 + 1;

        bool vy0 = (unsigned)y0 < (unsigned)H;
        bool vy1 = (unsigned)y1 < (unsigned)H;
        bool vx0 = (unsigned)x0 < (unsigned)W;
        bool vx1 = (unsigned)x1 < (unsigned)W;

        int cy0 = min(max(y0, 0), H - 1) * W;
        int cy1 = min(max(y1, 0), H - 1) * W;
        int cx0 = min(max(x0, 0), W - 1);
        int cx1 = min(max(x1, 0), W - 1);

        float a00 = (vy0 && vx0) ? (1.f - wy) * (1.f - wx) * m : 0.f;
        float a01 = (vy0 && vx1) ? (1.f - wy) * wx * m         : 0.f;
        float a10 = (vy1 && vx0) ? wy * (1.f - wx) * m         : 0.f;
        float a11 = (vy1 && vx1) ? wy * wx * m                 : 0.f;

        int o00 = cy0 + cx0, o01 = cy0 + cx1, o10 = cy1 + cx0, o11 = cy1 + cx1;

#pragma unroll
        for (int cc = 0; cc < 6; ++cc) {
            const float* xc = xn + (c_lo + cc) * HW;
            float s = xc[o00] * a00;
            s = fmaf(xc[o01], a01, s);
            s = fmaf(xc[o10], a10, s);
            s = fmaf(xc[o11], a11, s);
            sv[cc] = s;
        }
    };

    float acc[6];
#pragma unroll
    for (int j = 0; j < 6; ++j) acc[j] = 0.f;

    {
        float sv[6];
        sample_tap(0, sv);
#pragma unroll
        for (int cc = 0; cc < 6; ++cc) smp0[(c_lo + cc) * 64 + lane] = sv[cc];
    }
    __syncthreads();

#pragma unroll 1
    for (int k = 0; k < 9; ++k) {
        float* cur = (k & 1) ? smp1 : smp0;
        float* nxt = (k & 1) ? smp0 : smp1;

        // issue next tap's gathers first (in flight under the FMAs below)
        float nv[6];
        if (k < 8) sample_tap(k + 1, nv);

        // accumulate tap k into this wave's 6 output channels
        const float* dwk = ws + WS_DWO + k * C * C;
#pragma unroll
        for (int cb = 0; cb < 6; ++cb) {
            float s8[8];
#pragma unroll
            for (int i = 0; i < 8; ++i) s8[i] = cur[(cb * 8 + i) * 64 + lane];
#pragma unroll
            for (int j = 0; j < 6; ++j) {
                const float* wr = dwk + (o_lo + j) * C + cb * 8;   // SGPR, s_load_dwordx8
#pragma unroll
                for (int i = 0; i < 8; ++i) acc[j] = fmaf(s8[i], wr[i], acc[j]);
            }
        }

        if (k < 8) {
#pragma unroll
            for (int cc = 0; cc < 6; ++cc) nxt[(c_lo + cc) * 64 + lane] = nv[cc];
        }
        __syncthreads();
    }

    // ================= epilogue: BN + residual + ReLU, no reduce =================
    const float* sc = ws + WS_SC;
    const float* bi = ws + WS_BI;
    int base = n * C * HW + hw;
#pragma unroll
    for (int j = 0; j < 6; ++j) {
        int o = o_lo + j;                          // wave-uniform
        float v = fmaf(acc[j], sc[o], bi[o]) + x[base + o * HW];
        out[base + o * HW] = fmaxf(v, 0.f);
    }
}

// ---------------------------------------------------------------------------
extern "C" void kernel_launch(void* const* d_in, const int* in_sizes, int n_in,
                              void* d_out, int out_size, void* d_ws, size_t ws_size,
                              hipStream_t stream)
{
    const float* x     = (const float*)d_in[0];
    const float* tm_w  = (const float*)d_in[1];
    const float* tm_b  = (const float*)d_in[2];
    const float* tr_w  = (const float*)d_in[3];
    const float* tr_b  = (const float*)d_in[4];
    const float* mk_w  = (const float*)d_in[5];
    const float* mk_b  = (const float*)d_in[6];
    const float* dw    = (const float*)d_in[7];
    const float* gamma = (const float*)d_in[8];
    const float* beta  = (const float*)d_in[9];
    const float* rmean = (const float*)d_in[10];
    const float* rvar  = (const float*)d_in[11];
    float* out = (float*)d_out;
    float* ws  = (float*)d_ws;

    hipLaunchKernelGGL(prep_kernel, dim3((DWO_SZ + 255) / 256), dim3(256), 0, stream,
                       tm_w, tr_w, mk_w, dw, gamma, beta, rmean, rvar, ws);
    hipLaunchKernelGGL(fused_kernel, dim3(P / 64), dim3(512), 0, stream,
                       x, tm_b, tr_b, mk_b, ws, out);
}

// Round 7
// 186.797 us; speedup vs baseline: 1.6233x; 1.6233x over previous
//
#include <hip/hip_runtime.h>
#include <math.h>
#include <stdint.h>

namespace {
constexpr int N = 8, C = 48, H = 96, W = 72;
constexpr int HW = H * W;        // 6912 = 108*64
constexpr int P = N * HW;        // 55296
constexpr float BN_EPS = 1e-5f;

// ws layout (BYTE offsets)
// A_conv frags: [pair5][kstep3][lane64][8] bf16  (M=16 rows, row15=0)
constexpr int WS_ACONV = 0;
constexpr int ACONV_EL = 5 * 3 * 64 * 8;          // 7680 elems
// A_def frags:  [pair5][kstep3][mtile3][lane64][8] bf16 (M=48)
constexpr int WS_ADEF  = WS_ACONV + ACONV_EL * 2; // 15360
constexpr int ADEF_EL  = 5 * 3 * 3 * 64 * 8;      // 23040 elems
constexpr int WS_SC    = WS_ADEF + ADEF_EL * 2;   // 61440: f32[48]
constexpr int WS_BI    = WS_SC + 48 * 4;          // 61632: f32[48]

typedef __attribute__((ext_vector_type(8))) short  bf16x8;
typedef __attribute__((ext_vector_type(4))) float  f32x4;
}

__device__ __forceinline__ unsigned short rne_bf16(float f) {
    unsigned u = __builtin_bit_cast(unsigned, f);
    return (unsigned short)((u + 0x7FFFu + ((u >> 16) & 1u)) >> 16);
}
__device__ __forceinline__ unsigned short f2bf(float f) {   // round-half-up (cheap)
    unsigned u = __builtin_bit_cast(unsigned, f);
    return (unsigned short)((u + 0x8000u) >> 16);
}

// ---------------------------------------------------------------------------
// prep: write MFMA A-fragments (fragment-linear, bf16) + BN fold.
// K index = tap*48 + c, grouped in 5 pairs of K=96 (taps {2p,2p+1}, tap9=0).
// Fragment: lane l -> row (l&15) [+16*mtile], k = kstep*32 + (l>>4)*8 + i.
// ---------------------------------------------------------------------------
__global__ void prep_kernel(const float* __restrict__ tm_w, const float* __restrict__ tr_w,
                            const float* __restrict__ mk_w, const float* __restrict__ dw,
                            const float* __restrict__ gamma, const float* __restrict__ beta,
                            const float* __restrict__ rmean, const float* __restrict__ rvar,
                            unsigned char* __restrict__ wsb)
{
    int tid = blockIdx.x * blockDim.x + threadIdx.x;

    if (tid < ACONV_EL) {
        int i  = tid & 7;
        int l  = (tid >> 3) & 63;
        int r  = tid >> 9;            // pair*3 + kstep
        int ks = r % 3, p = r / 3;
        int o  = l & 15;
        int Kg = p * 96 + ks * 32 + ((l >> 4) * 8) + i;
        int t  = Kg / 48, c = Kg % 48;
        float v = 0.f;
        if (o < 15 && t < 9) {
            if (o < 4)      v = tm_w[(o * C + c) * 9 + t];
            else if (o < 6) v = tr_w[((o - 4) * C + c) * 9 + t];
            else            v = mk_w[((o - 6) * C + c) * 9 + t];
        }
        ((unsigned short*)(wsb + WS_ACONV))[tid] = rne_bf16(v);
    }
    int t2 = tid - ACONV_EL;
    if (t2 >= 0 && t2 < ADEF_EL) {
        int i  = t2 & 7;
        int l  = (t2 >> 3) & 63;
        int r2 = t2 >> 9;             // (pair*3+kstep)*3 + mtile
        int mt = r2 % 3;
        int r3 = r2 / 3;
        int ks = r3 % 3, p = r3 / 3;
        int o  = mt * 16 + (l & 15);
        int Kg = p * 96 + ks * 32 + ((l >> 4) * 8) + i;
        int t  = Kg / 48, c = Kg % 48;
        float v = (t < 9) ? dw[(o * C + c) * 9 + t] : 0.f;
        ((unsigned short*)(wsb + WS_ADEF))[t2] = rne_bf16(v);
    }
    if (tid < C) {
        float sc = gamma[tid] * rsqrtf(rvar[tid] + BN_EPS);
        ((float*)(wsb + WS_SC))[tid] = sc;
        ((float*)(wsb + WS_BI))[tid] = beta[tid] - rmean[tid] * sc;
    }
}

// ---------------------------------------------------------------------------
// Fused MFMA kernel. Block = 256 thr = 4 waves, 64 pixels.
// Pass1: conv15 GEMM (M=16) -> offsets in LDS.
// Pass2: deform-sample staging + GEMM (M=48) -> BN+res+ReLU.
// B staged per tap-pair in LDS [64px][128K] bf16, XOR-swizzled, double-buffered.
// Wave wv: N-tile = px 16wv..16wv+15 (all M-tiles). Staging: wave wv samples
// channels 12wv..12wv+11 for each tap (wave-uniform channel base).
// XCD swizzle: blockIdx&7 = batch n.
// ---------------------------------------------------------------------------
__global__ __launch_bounds__(256, 4) void fused_kernel(
    const float* __restrict__ x,
    const float* __restrict__ tm_b, const float* __restrict__ tr_b,
    const float* __restrict__ mk_b,
    const unsigned char* __restrict__ wsb,
    float* __restrict__ out)
{
    __shared__ __align__(16) unsigned char lds[39680];
    // [0,16384): samp buf0   [16384,32768): samp buf1 (aliased by convout[16][64] f32)
    // [32768,39680): offs[9][3][64] f32
    unsigned char* buf[2] = { lds, lds + 16384 };
    float* convout = (float*)(lds + 16384);
    float* offs    = (float*)(lds + 32768);

    const int tid = threadIdx.x;
    const int l   = tid & 63;
    const int wv  = __builtin_amdgcn_readfirstlane(tid >> 6);   // 0..3

    const int b    = blockIdx.x;
    const int n    = b & 7;                 // XCD-aligned batch
    const int tile = b >> 3;                // 0..107
    const int hw   = tile * 64 + l;         // this thread's staging pixel
    const int h    = hw / W;
    const int w    = hw - h * W;

    const float* xn = x + (size_t)n * C * HW;
    const int cbase = 12 * wv;              // staging channel slice

    // C-frag pixel (N-tile col) and B-frag addressing
    const int pxc  = (wv << 4) | (l & 15);
    const int bb   = pxc * 256 + ((l >> 4) << 4);   // + ks*64, then XOR
    const int xorv = (l & 15) << 4;

    const short* Ac = (const short*)(wsb + WS_ACONV);
    const short* Ad = (const short*)(wsb + WS_ADEF);

    // ---- staging helpers ----
    auto write_stage = [&](unsigned char* bp, const float sv[24]) {
#pragma unroll
        for (int tl = 0; tl < 2; ++tl)
#pragma unroll
            for (int cc = 0; cc < 6; ++cc) {
                unsigned val = (unsigned)f2bf(sv[tl * 12 + 2 * cc]) |
                               ((unsigned)f2bf(sv[tl * 12 + 2 * cc + 1]) << 16);
                int Klocal = tl * 48 + cbase + 2 * cc;
                int byte   = (l * 256 + Klocal * 2) ^ ((l & 15) << 4);
                *(unsigned*)(bp + byte) = val;
            }
    };

    auto sample_conv = [&](int p, float sv[24]) {
#pragma unroll
        for (int tl = 0; tl < 2; ++tl) {
            int t = 2 * p + tl;
            bool tv = t < 9;
            int dy = t / 3 - 1, dx = t % 3 - 1;
            int hh = h + dy, ww = w + dx;
            bool v = tv && ((unsigned)hh < (unsigned)H) && ((unsigned)ww < (unsigned)W);
            int off = v ? hh * W + ww : 0;
#pragma unroll
            for (int cc = 0; cc < 12; ++cc) {
                const float* xc = xn + (cbase + cc) * HW;
                sv[tl * 12 + cc] = v ? xc[off] : 0.f;
            }
        }
    };

    auto sample_def = [&](int p, float sv[24]) {
#pragma unroll
        for (int tl = 0; tl < 2; ++tl) {
            int t = 2 * p + tl;
            if (t >= 9) {
#pragma unroll
                for (int cc = 0; cc < 12; ++cc) sv[tl * 12 + cc] = 0.f;
            } else {
                float o_y = offs[(t * 3 + 0) * 64 + l];
                float o_x = offs[(t * 3 + 1) * 64 + l];
                float m   = offs[(t * 3 + 2) * 64 + l];
                float py  = (float)(h + t / 3 - 1) + o_y;
                float pxf = (float)(w + t % 3 - 1) + o_x;
                float y0f = floorf(py), x0f = floorf(pxf);
                float wy = py - y0f, wx = pxf - x0f;
                int y0 = (int)y0f, x0 = (int)x0f;
                int y1 = y0 + 1,  x1 = x0 + 1;
                bool vy0 = (unsigned)y0 < (unsigned)H;
                bool vy1 = (unsigned)y1 < (unsigned)H;
                bool vx0 = (unsigned)x0 < (unsigned)W;
                bool vx1 = (unsigned)x1 < (unsigned)W;
                int cy0 = min(max(y0, 0), H - 1) * W;
                int cy1 = min(max(y1, 0), H - 1) * W;
                int cx0 = min(max(x0, 0), W - 1);
                int cx1 = min(max(x1, 0), W - 1);
                float a00 = (vy0 && vx0) ? (1.f - wy) * (1.f - wx) * m : 0.f;
                float a01 = (vy0 && vx1) ? (1.f - wy) * wx * m         : 0.f;
                float a10 = (vy1 && vx0) ? wy * (1.f - wx) * m         : 0.f;
                float a11 = (vy1 && vx1) ? wy * wx * m                 : 0.f;
                int o00 = cy0 + cx0, o01 = cy0 + cx1, o10 = cy1 + cx0, o11 = cy1 + cx1;
#pragma unroll
                for (int cc = 0; cc < 12; ++cc) {
                    const float* xc = xn + (cbase + cc) * HW;
                    float s = xc[o00] * a00;
                    s = fmaf(xc[o01], a01, s);
                    s = fmaf(xc[o10], a10, s);
                    s = fmaf(xc[o11], a11, s);
                    sv[tl * 12 + cc] = s;
                }
            }
        }
    };

    // ================= Pass 1: conv15 GEMM =================
    f32x4 cacc = {0.f, 0.f, 0.f, 0.f};
    {
        float sv0[24];
        sample_conv(0, sv0);
        write_stage(buf[0], sv0);
    }
    __syncthreads();
#pragma unroll
    for (int p = 0; p < 5; ++p) {
        float sv[24];
        if (p < 4) sample_conv(p + 1, sv);
        const unsigned char* cur = buf[p & 1];
#pragma unroll
        for (int ks = 0; ks < 3; ++ks) {
            bf16x8 bfr = *(const bf16x8*)(cur + ((bb + ks * 64) ^ xorv));
            bf16x8 afr = *(const bf16x8*)(Ac + ((p * 3 + ks) * 64 + l) * 8);
            cacc = __builtin_amdgcn_mfma_f32_16x16x32_bf16(afr, bfr, cacc, 0, 0, 0);
        }
        if (p < 4) write_stage(buf[(p + 1) & 1], sv);
        __syncthreads();
    }

    // conv C-frag -> convout (aliases buf1; buf1's last read was pair3, done)
    {
        int rowg = (l >> 4) * 4;
#pragma unroll
        for (int r = 0; r < 4; ++r)
            convout[(rowg + r) * 64 + pxc] = cacc[r];
    }
    __syncthreads();

    // offsets: thread t -> pixel t&63, k set {kk, kk+4, kk+8}
    {
        int pxo = tid & 63;
        int kk  = tid >> 6;
        float T0 = convout[0 * 64 + pxo] + tm_b[0];
        float T1 = convout[1 * 64 + pxo] + tm_b[1];
        float T2 = convout[2 * 64 + pxo] + tm_b[2];
        float T3 = convout[3 * 64 + pxo] + tm_b[3];
        float R0 = convout[4 * 64 + pxo] + tr_b[0];
        float R1 = convout[5 * 64 + pxo] + tr_b[1];
#pragma unroll
        for (int j = 0; j < 3; ++j) {
            int k = kk + 4 * j;
            if (k < 9) {
                float ry = (float)(k / 3) - 1.f;
                float rx = (float)(k % 3) - 1.f;
                offs[(k * 3 + 0) * 64 + pxo] = fmaf(T0, ry, fmaf(T1, rx, R0)) - ry;
                offs[(k * 3 + 1) * 64 + pxo] = fmaf(T2, ry, fmaf(T3, rx, R1)) - rx;
                offs[(k * 3 + 2) * 64 + pxo] = convout[(6 + k) * 64 + pxo] + mk_b[k];
            }
        }
    }
    __syncthreads();

    // ================= Pass 2: deform GEMM =================
    f32x4 dacc[3];
#pragma unroll
    for (int mt = 0; mt < 3; ++mt) dacc[mt] = (f32x4){0.f, 0.f, 0.f, 0.f};

    {
        float sv0[24];
        sample_def(0, sv0);
        write_stage(buf[0], sv0);
    }
    __syncthreads();
#pragma unroll
    for (int p = 0; p < 5; ++p) {
        float sv[24];
        if (p < 4) sample_def(p + 1, sv);
        const unsigned char* cur = buf[p & 1];
#pragma unroll
        for (int ks = 0; ks < 3; ++ks) {
            bf16x8 bfr = *(const bf16x8*)(cur + ((bb + ks * 64) ^ xorv));
#pragma unroll
            for (int mt = 0; mt < 3; ++mt) {
                bf16x8 afr = *(const bf16x8*)(Ad + (((p * 3 + ks) * 3 + mt) * 64 + l) * 8);
                dacc[mt] = __builtin_amdgcn_mfma_f32_16x16x32_bf16(afr, bfr, dacc[mt], 0, 0, 0);
            }
        }
        if (p < 4) write_stage(buf[(p + 1) & 1], sv);
        __syncthreads();
    }

    // ================= epilogue: BN + residual + ReLU =================
    {
        const float* sc = (const float*)(wsb + WS_SC);
        const float* bi = (const float*)(wsb + WS_BI);
        int rowg = (l >> 4) * 4;
        int pbase = n * C * HW + tile * 64 + pxc;
#pragma unroll
        for (int mt = 0; mt < 3; ++mt)
#pragma unroll
            for (int r = 0; r < 4; ++r) {
                int o = mt * 16 + rowg + r;
                int addr = pbase + o * HW;
                float v = fmaf(dacc[mt][r], sc[o], bi[o]) + x[addr];
                out[addr] = fmaxf(v, 0.f);
            }
    }
}

// ---------------------------------------------------------------------------
extern "C" void kernel_launch(void* const* d_in, const int* in_sizes, int n_in,
                              void* d_out, int out_size, void* d_ws, size_t ws_size,
                              hipStream_t stream)
{
    const float* x     = (const float*)d_in[0];
    const float* tm_w  = (const float*)d_in[1];
    const float* tm_b  = (const float*)d_in[2];
    const float* tr_w  = (const float*)d_in[3];
    const float* tr_b  = (const float*)d_in[4];
    const float* mk_w  = (const float*)d_in[5];
    const float* mk_b  = (const float*)d_in[6];
    const float* dw    = (const float*)d_in[7];
    const float* gamma = (const float*)d_in[8];
    const float* beta  = (const float*)d_in[9];
    const float* rmean = (const float*)d_in[10];
    const float* rvar  = (const float*)d_in[11];
    float* out = (float*)d_out;
    unsigned char* wsb = (unsigned char*)d_ws;

    int prep_threads = ACONV_EL + ADEF_EL;   // 30720
    hipLaunchKernelGGL(prep_kernel, dim3((prep_threads + 255) / 256), dim3(256), 0, stream,
                       tm_w, tr_w, mk_w, dw, gamma, beta, rmean, rvar, wsb);
    hipLaunchKernelGGL(fused_kernel, dim3(P / 64), dim3(256), 0, stream,
                       x, tm_b, tr_b, mk_b, wsb, out);
}

// Round 12
// 122.963 us; speedup vs baseline: 2.4661x; 1.5191x over previous
//
#include <hip/hip_runtime.h>
#include <math.h>
#include <stdint.h>

namespace {
constexpr int N = 8, C = 48, H = 96, W = 72;
constexpr int HW = H * W;        // 6912 = 108*64
constexpr int P = N * HW;        // 55296
constexpr float BN_EPS = 1e-5f;

// K = tap*48 + c, padded to 448 (14 ksteps of 32). taps 0..8 real, pad=0.
constexpr int KSTEPS = 14;

// ws layout (BYTE offsets)
constexpr int WS_ACONV = 0;                        // [ks14][lane64][8] bf16
constexpr int ACONV_EL = KSTEPS * 64 * 8;          // 7168
constexpr int WS_ADEF  = WS_ACONV + ACONV_EL * 2;  // 14336; [ks14][mt3][lane64][8] bf16
constexpr int ADEF_EL  = KSTEPS * 3 * 64 * 8;      // 21504
constexpr int WS_SC    = WS_ADEF + ADEF_EL * 2;    // 57344: f32[48]
constexpr int WS_BI    = WS_SC + 192;              // 57536: f32[48]
constexpr int WS_XT    = 57728;                    // fp16 NHWC x: [n][hw][48]
// total = 57728 + P*48*2 = 5,366,144 B

typedef __attribute__((ext_vector_type(8))) short     bf16x8;
typedef __attribute__((ext_vector_type(4))) float     f32x4;
typedef __attribute__((ext_vector_type(8))) _Float16  half8;
typedef __attribute__((ext_vector_type(4))) unsigned  u32x4;
typedef __attribute__((ext_vector_type(2))) unsigned  u32x2;
}

__device__ __forceinline__ unsigned short rne_bf16(float f) {
    unsigned u = __builtin_bit_cast(unsigned, f);
    return (unsigned short)((u + 0x7FFFu + ((u >> 16) & 1u)) >> 16);
}
__device__ __forceinline__ unsigned f2bf2(float a, float b) {   // two round-half-up bf16 in a u32
    unsigned ua = __builtin_bit_cast(unsigned, a);
    unsigned ub = __builtin_bit_cast(unsigned, b);
    return ((ua + 0x8000u) >> 16) | (((ub + 0x8000u) >> 16) << 16);
}

// ---------------------------------------------------------------------------
// prep: MFMA A-fragments (bf16, fragment-linear) + BN fold.
// Fragment: lane l -> row (l&15)[+16*mt], k = ks*32 + (l>>4)*8 + i.
// ---------------------------------------------------------------------------
__global__ void prep_kernel(const float* __restrict__ tm_w, const float* __restrict__ tr_w,
                            const float* __restrict__ mk_w, const float* __restrict__ dw,
                            const float* __restrict__ gamma, const float* __restrict__ beta,
                            const float* __restrict__ rmean, const float* __restrict__ rvar,
                            unsigned char* __restrict__ wsb)
{
    int tid = blockIdx.x * blockDim.x + threadIdx.x;

    if (tid < ACONV_EL) {
        int i  = tid & 7;
        int l  = (tid >> 3) & 63;
        int ks = tid >> 9;
        int o  = l & 15;
        int Kg = ks * 32 + ((l >> 4) * 8) + i;
        int t  = Kg / 48, c = Kg % 48;
        float v = 0.f;
        if (o < 15 && t < 9) {
            if (o < 4)      v = tm_w[(o * C + c) * 9 + t];
            else if (o < 6) v = tr_w[((o - 4) * C + c) * 9 + t];
            else            v = mk_w[((o - 6) * C + c) * 9 + t];
        }
        ((unsigned short*)(wsb + WS_ACONV))[tid] = rne_bf16(v);
    }
    int t2 = tid - ACONV_EL;
    if (t2 >= 0 && t2 < ADEF_EL) {
        int i  = t2 & 7;
        int l  = (t2 >> 3) & 63;
        int r2 = t2 >> 9;             // ks*3 + mt
        int mt = r2 % 3;
        int ks = r2 / 3;
        int o  = mt * 16 + (l & 15);
        int Kg = ks * 32 + ((l >> 4) * 8) + i;
        int t  = Kg / 48, c = Kg % 48;
        float v = (t < 9) ? dw[(o * C + c) * 9 + t] : 0.f;
        ((unsigned short*)(wsb + WS_ADEF))[t2] = rne_bf16(v);
    }
    if (tid < C) {
        float sc = gamma[tid] * rsqrtf(rvar[tid] + BN_EPS);
        ((float*)(wsb + WS_SC))[tid] = sc;
        ((float*)(wsb + WS_BI))[tid] = beta[tid] - rmean[tid] * sc;
    }
}

// ---------------------------------------------------------------------------
// transpose: x NCHW f32 -> xT NHWC fp16 (channel contiguous -> vector gathers).
// ---------------------------------------------------------------------------
__global__ __launch_bounds__(256) void transpose_kernel(
    const float* __restrict__ x, unsigned char* __restrict__ wsb)
{
    __shared__ float tile[48][64];
    int tid = threadIdx.x;
    int b   = blockIdx.x;
    int n   = b & 7;
    int hw0 = (b >> 3) * 64;

#pragma unroll
    for (int it = 0; it < 12; ++it) {
        int c = it * 4 + (tid >> 6);
        tile[c][tid & 63] = x[((size_t)(n * C + c)) * HW + hw0 + (tid & 63)];
    }
    __syncthreads();

    int px = tid >> 2;
    int cq = tid & 3;
    unsigned short* xt = (unsigned short*)(wsb + WS_XT);
    size_t base = ((size_t)(n * HW + hw0 + px)) * 48 + cq * 12;
    unsigned pk[6];
#pragma unroll
    for (int k = 0; k < 6; ++k) {
        _Float16 h0 = (_Float16)tile[cq * 12 + 2 * k][px];
        _Float16 h1 = (_Float16)tile[cq * 12 + 2 * k + 1][px];
        pk[k] = (unsigned)__builtin_bit_cast(unsigned short, h0) |
                ((unsigned)__builtin_bit_cast(unsigned short, h1) << 16);
    }
#pragma unroll
    for (int k = 0; k < 3; ++k)
        *(u32x2*)(xt + base + k * 4) = (u32x2){pk[2 * k], pk[2 * k + 1]};
}

// ---------------------------------------------------------------------------
// Fused kernel: 576 threads = 9 waves = 9 taps, 64 pixels/block.
// Thread (wave=tap wv, lane=px l) owns task (px,tap): conv-tap stage, offs in
// regs, bilinear sample (fp16 NHWC vector gathers), B-tile write.
// B-tile [64 px][448 K] bf16 (896 B/row), XOR-swizzled. K-pad (432..447)
// zero-filled ONCE at start (A is zero there, but 0*garbage-NaN = NaN -> the
// r8 failure; fmax(NaN,0)=0 silently zeroed outputs).
// ---------------------------------------------------------------------------
__global__ __launch_bounds__(576, 5) void fused_kernel(
    const float* __restrict__ x,
    const float* __restrict__ tm_b, const float* __restrict__ tr_b,
    const float* __restrict__ mk_b,
    const unsigned char* __restrict__ wsb,
    float* __restrict__ out)
{
    __shared__ __align__(16) unsigned char lds[64 * 896 + 16 * 64 * 4];  // 61,440 B
    float* convout = (float*)(lds + 64 * 896);

    const int tid = threadIdx.x;
    const int l   = tid & 63;
    const int wv  = __builtin_amdgcn_readfirstlane(tid >> 6);   // 0..8 = tap

    const int b    = blockIdx.x;
    const int n    = b & 7;
    const int tile = b >> 3;
    const int hw   = tile * 64 + l;
    const int ph   = hw / W;
    const int pw   = hw - ph * W;

    const unsigned short* xtn = (const unsigned short*)(wsb + WS_XT) + (size_t)n * HW * 48;
    const int swz = (l & 7) << 4;
    const int rowbase = l * 896 + wv * 96;

    // ---- zero the K-pad (logical bytes 864..895 of each row): neither pass
    // writes it, both passes read it. One-time, before bar 1.
    if (wv == 0) {
        *(u32x4*)(lds + ((l * 896 + 864) ^ swz)) = (u32x4){0u, 0u, 0u, 0u};
        *(u32x4*)(lds + ((l * 896 + 880) ^ swz)) = (u32x4){0u, 0u, 0u, 0u};
    }

    // ---------------- conv staging: integer tap wv ----------------
    {
        int dy = wv / 3 - 1, dx = wv % 3 - 1;
        int hh = ph + dy, ww = pw + dx;
        bool v = ((unsigned)hh < (unsigned)H) && ((unsigned)ww < (unsigned)W);
        const unsigned short* src = xtn + (size_t)(v ? hh * W + ww : 0) * 48;
#pragma unroll
        for (int half = 0; half < 2; ++half) {
            half8 cv[3];
#pragma unroll
            for (int jc = 0; jc < 3; ++jc)
                cv[jc] = v ? *(const half8*)(src + half * 24 + jc * 8) : (half8)0;
#pragma unroll
            for (int jc = 0; jc < 3; ++jc) {
                u32x4 pk;
#pragma unroll
                for (int p = 0; p < 4; ++p)
                    pk[p] = f2bf2((float)cv[jc][2 * p], (float)cv[jc][2 * p + 1]);
                *(u32x4*)(lds + ((rowbase + half * 48 + jc * 16) ^ swz)) = pk;
            }
        }
    }
    __syncthreads();   // ---- bar 1

    // ---------------- conv GEMM (waves 0-3) + convout ----------------
    if (wv < 4) {
        const short* Ac = (const short*)(wsb + WS_ACONV);
        f32x4 cacc = {0.f, 0.f, 0.f, 0.f};
        int pxc = wv * 16 + (l & 15);
        int bbase = pxc * 896 + ((l >> 4) << 4);
#pragma unroll
        for (int ks = 0; ks < KSTEPS; ++ks) {
            bf16x8 bfr = *(const bf16x8*)(lds + ((bbase + ks * 64) ^ swz));
            bf16x8 afr = *(const bf16x8*)(Ac + (ks * 64 + l) * 8);
            cacc = __builtin_amdgcn_mfma_f32_16x16x32_bf16(afr, bfr, cacc, 0, 0, 0);
        }
        int rowg = (l >> 4) * 4;
#pragma unroll
        for (int r = 0; r < 4; ++r)
            convout[(rowg + r) * 64 + pxc] = cacc[r];
    }
    __syncthreads();   // ---- bar 2

    // ---------------- offsets for (tap wv, px l) in registers ----------------
    float o_y, o_x, msk;
    {
        float T0 = convout[0 * 64 + l] + tm_b[0];
        float T1 = convout[1 * 64 + l] + tm_b[1];
        float T2 = convout[2 * 64 + l] + tm_b[2];
        float T3 = convout[3 * 64 + l] + tm_b[3];
        float R0 = convout[4 * 64 + l] + tr_b[0];
        float R1 = convout[5 * 64 + l] + tr_b[1];
        float ry = (float)(wv / 3) - 1.f;
        float rx = (float)(wv % 3) - 1.f;
        o_y = fmaf(T0, ry, fmaf(T1, rx, R0)) - ry;
        o_x = fmaf(T2, ry, fmaf(T3, rx, R1)) - rx;
        msk = convout[(6 + wv) * 64 + l] + mk_b[wv];
    }

    // ---------------- deform staging: bilinear sample tap wv ----------------
    {
        float py  = (float)(ph + wv / 3 - 1) + o_y;
        float pxf = (float)(pw + wv % 3 - 1) + o_x;
        float y0f = floorf(py), x0f = floorf(pxf);
        float wy = py - y0f, wx = pxf - x0f;
        int y0 = (int)y0f, x0 = (int)x0f;
        int y1 = y0 + 1,  x1 = x0 + 1;
        bool vy0 = (unsigned)y0 < (unsigned)H;
        bool vy1 = (unsigned)y1 < (unsigned)H;
        bool vx0 = (unsigned)x0 < (unsigned)W;
        bool vx1 = (unsigned)x1 < (unsigned)W;
        int cy0 = min(max(y0, 0), H - 1) * W;
        int cy1 = min(max(y1, 0), H - 1) * W;
        int cx0 = min(max(x0, 0), W - 1);
        int cx1 = min(max(x1, 0), W - 1);
        float a00 = (vy0 && vx0) ? (1.f - wy) * (1.f - wx) * msk : 0.f;
        float a01 = (vy0 && vx1) ? (1.f - wy) * wx * msk         : 0.f;
        float a10 = (vy1 && vx0) ? wy * (1.f - wx) * msk         : 0.f;
        float a11 = (vy1 && vx1) ? wy * wx * msk                 : 0.f;
        const unsigned short* r00 = xtn + (size_t)(cy0 + cx0) * 48;
        const unsigned short* r01 = xtn + (size_t)(cy0 + cx1) * 48;
        const unsigned short* r10 = xtn + (size_t)(cy1 + cx0) * 48;
        const unsigned short* r11 = xtn + (size_t)(cy1 + cx1) * 48;

#pragma unroll
        for (int half = 0; half < 2; ++half) {
            half8 c00[3], c01[3], c10[3], c11[3];
#pragma unroll
            for (int jc = 0; jc < 3; ++jc) {
                c00[jc] = *(const half8*)(r00 + half * 24 + jc * 8);
                c01[jc] = *(const half8*)(r01 + half * 24 + jc * 8);
                c10[jc] = *(const half8*)(r10 + half * 24 + jc * 8);
                c11[jc] = *(const half8*)(r11 + half * 24 + jc * 8);
            }
#pragma unroll
            for (int jc = 0; jc < 3; ++jc) {
                u32x4 pk;
#pragma unroll
                for (int p = 0; p < 4; ++p) {
                    float e0 = (float)c00[jc][2 * p] * a00;
                    e0 = fmaf((float)c01[jc][2 * p], a01, e0);
                    e0 = fmaf((float)c10[jc][2 * p], a10, e0);
                    e0 = fmaf((float)c11[jc][2 * p], a11, e0);
                    float e1 = (float)c00[jc][2 * p + 1] * a00;
                    e1 = fmaf((float)c01[jc][2 * p + 1], a01, e1);
                    e1 = fmaf((float)c10[jc][2 * p + 1], a10, e1);
                    e1 = fmaf((float)c11[jc][2 * p + 1], a11, e1);
                    pk[p] = f2bf2(e0, e1);
                }
                *(u32x4*)(lds + ((rowbase + half * 48 + jc * 16) ^ swz)) = pk;
            }
        }
    }
    __syncthreads();   // ---- bar 3

    // ---------------- deform GEMM: 12 C-tiles over 9 waves + epilogue ----------------
    const short* Ad = (const short*)(wsb + WS_ADEF);
    const float* sc = (const float*)(wsb + WS_SC);
    const float* bi = (const float*)(wsb + WS_BI);

#pragma unroll
    for (int rep = 0; rep < 2; ++rep) {
        int t = wv + rep * 9;
        if (t < 12) {
            int mt = t >> 2, nt = t & 3;
            int pxc = nt * 16 + (l & 15);
            int bbase = pxc * 896 + ((l >> 4) << 4);
            f32x4 acc = {0.f, 0.f, 0.f, 0.f};
#pragma unroll
            for (int ks = 0; ks < KSTEPS; ++ks) {
                bf16x8 bfr = *(const bf16x8*)(lds + ((bbase + ks * 64) ^ swz));
                bf16x8 afr = *(const bf16x8*)(Ad + ((ks * 3 + mt) * 64 + l) * 8);
                acc = __builtin_amdgcn_mfma_f32_16x16x32_bf16(afr, bfr, acc, 0, 0, 0);
            }
            int rowg = (l >> 4) * 4;
#pragma unroll
            for (int r = 0; r < 4; ++r) {
                int o = mt * 16 + rowg + r;
                size_t addr = ((size_t)(n * C + o)) * HW + tile * 64 + pxc;
                float v = fmaf(acc[r], sc[o], bi[o]) + x[addr];
                out[addr] = fmaxf(v, 0.f);
            }
        }
    }
}

// ---------------------------------------------------------------------------
extern "C" void kernel_launch(void* const* d_in, const int* in_sizes, int n_in,
                              void* d_out, int out_size, void* d_ws, size_t ws_size,
                              hipStream_t stream)
{
    const float* x     = (const float*)d_in[0];
    const float* tm_w  = (const float*)d_in[1];
    const float* tm_b  = (const float*)d_in[2];
    const float* tr_w  = (const float*)d_in[3];
    const float* tr_b  = (const float*)d_in[4];
    const float* mk_w  = (const float*)d_in[5];
    const float* mk_b  = (const float*)d_in[6];
    const float* dw    = (const float*)d_in[7];
    const float* gamma = (const float*)d_in[8];
    const float* beta  = (const float*)d_in[9];
    const float* rmean = (const float*)d_in[10];
    const float* rvar  = (const float*)d_in[11];
    float* out = (float*)d_out;
    unsigned char* wsb = (unsigned char*)d_ws;

    int prep_threads = ACONV_EL + ADEF_EL;   // 28672
    hipLaunchKernelGGL(prep_kernel, dim3((prep_threads + 255) / 256), dim3(256), 0, stream,
                       tm_w, tr_w, mk_w, dw, gamma, beta, rmean, rvar, wsb);
    hipLaunchKernelGGL(transpose_kernel, dim3(P / 64), dim3(256), 0, stream, x, wsb);
    hipLaunchKernelGGL(fused_kernel, dim3(P / 64), dim3(576), 0, stream,
                       x, tm_b, tr_b, mk_b, wsb, out);
}

// Round 13
// 116.909 us; speedup vs baseline: 2.5938x; 1.0518x over previous
//
#include <hip/hip_runtime.h>
#include <math.h>
#include <stdint.h>

namespace {
constexpr int N = 8, C = 48, H = 96, W = 72;
constexpr int HW = H * W;        // 6912 = 144*48 = 108*64
constexpr int P = N * HW;        // 55296
constexpr float BN_EPS = 1e-5f;

// K = tap*48 + c, padded to 448 (14 ksteps of 32). taps 0..8 real, pad=0.
constexpr int KSTEPS = 14;
constexpr int PXB    = 48;       // pixels per fused block

// ws layout (BYTE offsets) — A-fragments now fp16
constexpr int WS_ACONV = 0;                        // [ks14][lane64][8] f16
constexpr int ACONV_EL = KSTEPS * 64 * 8;          // 7168
constexpr int WS_ADEF  = WS_ACONV + ACONV_EL * 2;  // 14336; [ks14][mt3][lane64][8] f16
constexpr int ADEF_EL  = KSTEPS * 3 * 64 * 8;      // 21504
constexpr int WS_SC    = WS_ADEF + ADEF_EL * 2;    // 57344: f32[48]
constexpr int WS_BI    = WS_SC + 192;              // 57536: f32[48]
constexpr int WS_XT    = 57728;                    // fp16 NHWC x: [n][hw][48]
// total = 57728 + P*48*2 = 5,366,144 B

typedef __attribute__((ext_vector_type(8))) _Float16  half8;
typedef __attribute__((ext_vector_type(4))) float     f32x4;
typedef __attribute__((ext_vector_type(4))) unsigned  u32x4;
typedef __attribute__((ext_vector_type(2))) unsigned  u32x2;
}

// ---------------------------------------------------------------------------
// transpose + prep fused: x NCHW f32 -> xT NHWC fp16; blocks < 112 also write
// the MFMA A-fragments (fp16, fragment-linear) and the BN fold.
// Fragment: lane l -> row (l&15)[+16*mt], k = ks*32 + (l>>4)*8 + i.
// ---------------------------------------------------------------------------
__global__ __launch_bounds__(256) void transpose_prep_kernel(
    const float* __restrict__ x,
    const float* __restrict__ tm_w, const float* __restrict__ tr_w,
    const float* __restrict__ mk_w, const float* __restrict__ dw,
    const float* __restrict__ gamma, const float* __restrict__ beta,
    const float* __restrict__ rmean, const float* __restrict__ rvar,
    unsigned char* __restrict__ wsb)
{
    __shared__ float tile[48][64];
    int tid = threadIdx.x;
    int b   = blockIdx.x;
    int n   = b & 7;
    int hw0 = (b >> 3) * 64;

#pragma unroll
    for (int it = 0; it < 12; ++it) {
        int c = it * 4 + (tid >> 6);
        tile[c][tid & 63] = x[((size_t)(n * C + c)) * HW + hw0 + (tid & 63)];
    }
    __syncthreads();

    {
        int px = tid >> 2;
        int cq = tid & 3;
        unsigned short* xt = (unsigned short*)(wsb + WS_XT);
        size_t base = ((size_t)(n * HW + hw0 + px)) * 48 + cq * 12;
        unsigned pk[6];
#pragma unroll
        for (int k = 0; k < 6; ++k) {
            _Float16 h0 = (_Float16)tile[cq * 12 + 2 * k][px];
            _Float16 h1 = (_Float16)tile[cq * 12 + 2 * k + 1][px];
            pk[k] = (unsigned)__builtin_bit_cast(unsigned short, h0) |
                    ((unsigned)__builtin_bit_cast(unsigned short, h1) << 16);
        }
#pragma unroll
        for (int k = 0; k < 3; ++k)
            *(u32x2*)(xt + base + k * 4) = (u32x2){pk[2 * k], pk[2 * k + 1]};
    }

    // ---- prep work piggybacked on the first 112 blocks ----
    int gtid = b * 256 + tid;
    if (gtid < ACONV_EL) {
        int i  = gtid & 7;
        int l  = (gtid >> 3) & 63;
        int ks = gtid >> 9;
        int o  = l & 15;
        int Kg = ks * 32 + ((l >> 4) * 8) + i;
        int t  = Kg / 48, c = Kg % 48;
        float v = 0.f;
        if (o < 15 && t < 9) {
            if (o < 4)      v = tm_w[(o * C + c) * 9 + t];
            else if (o < 6) v = tr_w[((o - 4) * C + c) * 9 + t];
            else            v = mk_w[((o - 6) * C + c) * 9 + t];
        }
        ((unsigned short*)(wsb + WS_ACONV))[gtid] =
            __builtin_bit_cast(unsigned short, (_Float16)v);
    }
    int t2 = gtid - ACONV_EL;
    if (t2 >= 0 && t2 < ADEF_EL) {
        int i  = t2 & 7;
        int l  = (t2 >> 3) & 63;
        int r2 = t2 >> 9;             // ks*3 + mt
        int mt = r2 % 3;
        int ks = r2 / 3;
        int o  = mt * 16 + (l & 15);
        int Kg = ks * 32 + ((l >> 4) * 8) + i;
        int t  = Kg / 48, c = Kg % 48;
        float v = (t < 9) ? dw[(o * C + c) * 9 + t] : 0.f;
        ((unsigned short*)(wsb + WS_ADEF))[t2] =
            __builtin_bit_cast(unsigned short, (_Float16)v);
    }
    if (gtid < C) {
        float sc = gamma[gtid] * rsqrtf(rvar[gtid] + BN_EPS);
        ((float*)(wsb + WS_SC))[gtid] = sc;
        ((float*)(wsb + WS_BI))[gtid] = beta[gtid] - rmean[gtid] * sc;
    }
}

// ---------------------------------------------------------------------------
// Fused kernel: 576 threads = 9 waves = 9 taps, 48 pixels/block (-> 46 KB LDS
// -> 3 blocks/CU -> 27 waves/CU for latency hiding).
// Thread (wave=tap wv, lane=px l<48) stages its (px,tap) task; conv GEMM on
// waves 0-2 (M=16, N=48); deform GEMM = 9 C-tiles, exactly one per wave.
// All matrix math in fp16 (mfma_f32_16x16x32_f16); bilinear blend in packed
// v_pk_fma_f16. B-tile [48 px][448 K] f16, XOR-swizzled; K-pad zeroed once.
// ---------------------------------------------------------------------------
__global__ __launch_bounds__(576, 5) void fused_kernel(
    const float* __restrict__ x,
    const float* __restrict__ tm_b, const float* __restrict__ tr_b,
    const float* __restrict__ mk_b,
    const unsigned char* __restrict__ wsb,
    float* __restrict__ out)
{
    __shared__ __align__(16) unsigned char lds[PXB * 896 + 16 * PXB * 4];  // 46,080 B
    float* convout = (float*)(lds + PXB * 896);

    const int tid = threadIdx.x;
    const int l   = tid & 63;
    const int wv  = __builtin_amdgcn_readfirstlane(tid >> 6);   // 0..8 = tap

    const int b    = blockIdx.x;
    const int n    = b & 7;                 // XCD-aligned batch
    const int tile = b >> 3;                // 0..143
    const int hw   = tile * PXB + (l < PXB ? l : PXB - 1);
    const int ph   = hw / W;
    const int pw   = hw - ph * W;

    const unsigned short* xtn = (const unsigned short*)(wsb + WS_XT) + (size_t)n * HW * 48;
    const int swz = (l & 7) << 4;
    const int rowbase = l * 896 + wv * 96;

    // ---- zero the K-pad (logical bytes 864..895 of each row) once ----
    if (wv == 0 && l < PXB) {
        *(u32x4*)(lds + ((l * 896 + 864) ^ swz)) = (u32x4){0u, 0u, 0u, 0u};
        *(u32x4*)(lds + ((l * 896 + 880) ^ swz)) = (u32x4){0u, 0u, 0u, 0u};
    }

    // ---------------- conv staging: integer tap wv (pure fp16 copy) ----------------
    if (l < PXB) {
        int dy = wv / 3 - 1, dx = wv % 3 - 1;
        int hh = ph + dy, ww = pw + dx;
        bool v = ((unsigned)hh < (unsigned)H) && ((unsigned)ww < (unsigned)W);
        const unsigned char* src = (const unsigned char*)(xtn + (size_t)(v ? hh * W + ww : 0) * 48);
#pragma unroll
        for (int j = 0; j < 6; ++j) {
            u32x4 val = v ? *(const u32x4*)(src + j * 16) : (u32x4){0u, 0u, 0u, 0u};
            *(u32x4*)(lds + ((rowbase + j * 16) ^ swz)) = val;
        }
    }
    __syncthreads();   // ---- bar 1

    // ---------------- conv GEMM (waves 0-2, M=16 x N=48) ----------------
    if (wv < 3) {
        const _Float16* Ac = (const _Float16*)(wsb + WS_ACONV);
        f32x4 cacc = {0.f, 0.f, 0.f, 0.f};
        int pxc = wv * 16 + (l & 15);
        int bbase = pxc * 896 + ((l >> 4) << 4);
#pragma unroll
        for (int ks = 0; ks < KSTEPS; ++ks) {
            half8 bfr = *(const half8*)(lds + ((bbase + ks * 64) ^ swz));
            half8 afr = *(const half8*)(Ac + (ks * 64 + l) * 8);
            cacc = __builtin_amdgcn_mfma_f32_16x16x32_f16(afr, bfr, cacc, 0, 0, 0);
        }
        int rowg = (l >> 4) * 4;
#pragma unroll
        for (int r = 0; r < 4; ++r)
            convout[(rowg + r) * PXB + pxc] = cacc[r];
    }
    __syncthreads();   // ---- bar 2

    // ---------------- offsets + bilinear sample for (tap wv, px l) ----------------
    if (l < PXB) {
        float T0 = convout[0 * PXB + l] + tm_b[0];
        float T1 = convout[1 * PXB + l] + tm_b[1];
        float T2 = convout[2 * PXB + l] + tm_b[2];
        float T3 = convout[3 * PXB + l] + tm_b[3];
        float R0 = convout[4 * PXB + l] + tr_b[0];
        float R1 = convout[5 * PXB + l] + tr_b[1];
        float ry = (float)(wv / 3) - 1.f;
        float rx = (float)(wv % 3) - 1.f;
        float o_y = fmaf(T0, ry, fmaf(T1, rx, R0)) - ry;
        float o_x = fmaf(T2, ry, fmaf(T3, rx, R1)) - rx;
        float msk = convout[(6 + wv) * PXB + l] + mk_b[wv];

        float py  = (float)(ph + wv / 3 - 1) + o_y;
        float pxf = (float)(pw + wv % 3 - 1) + o_x;
        float y0f = floorf(py), x0f = floorf(pxf);
        float wy = py - y0f, wx = pxf - x0f;
        int y0 = (int)y0f, x0 = (int)x0f;
        int y1 = y0 + 1,  x1 = x0 + 1;
        bool vy0 = (unsigned)y0 < (unsigned)H;
        bool vy1 = (unsigned)y1 < (unsigned)H;
        bool vx0 = (unsigned)x0 < (unsigned)W;
        bool vx1 = (unsigned)x1 < (unsigned)W;
        int cy0 = min(max(y0, 0), H - 1) * W;
        int cy1 = min(max(y1, 0), H - 1) * W;
        int cx0 = min(max(x0, 0), W - 1);
        int cx1 = min(max(x1, 0), W - 1);
        float a00 = (vy0 && vx0) ? (1.f - wy) * (1.f - wx) * msk : 0.f;
        float a01 = (vy0 && vx1) ? (1.f - wy) * wx * msk         : 0.f;
        float a10 = (vy1 && vx0) ? wy * (1.f - wx) * msk         : 0.f;
        float a11 = (vy1 && vx1) ? wy * wx * msk                 : 0.f;

        _Float16 w00 = (_Float16)a00, w01 = (_Float16)a01;
        _Float16 w10 = (_Float16)a10, w11 = (_Float16)a11;

        const _Float16* r00 = (const _Float16*)(xtn + (size_t)(cy0 + cx0) * 48);
        const _Float16* r01 = (const _Float16*)(xtn + (size_t)(cy0 + cx1) * 48);
        const _Float16* r10 = (const _Float16*)(xtn + (size_t)(cy1 + cx0) * 48);
        const _Float16* r11 = (const _Float16*)(xtn + (size_t)(cy1 + cx1) * 48);

#pragma unroll
        for (int ch = 0; ch < 2; ++ch) {          // 2 chunks of 3x half8 to cap VGPR
            half8 c00[3], c01[3], c10[3], c11[3];
#pragma unroll
            for (int j = 0; j < 3; ++j) {
                int jj = ch * 3 + j;
                c00[j] = *(const half8*)(r00 + jj * 8);
                c01[j] = *(const half8*)(r01 + jj * 8);
                c10[j] = *(const half8*)(r10 + jj * 8);
                c11[j] = *(const half8*)(r11 + jj * 8);
            }
#pragma unroll
            for (int j = 0; j < 3; ++j) {
                int jj = ch * 3 + j;
                half8 s = c00[j] * w00 + c01[j] * w01 + c10[j] * w10 + c11[j] * w11;
                *(u32x4*)(lds + ((rowbase + jj * 16) ^ swz)) = __builtin_bit_cast(u32x4, s);
            }
        }
    }
    __syncthreads();   // ---- bar 3

    // ---------------- deform GEMM: 9 C-tiles, one per wave + epilogue ----------------
    {
        const _Float16* Ad = (const _Float16*)(wsb + WS_ADEF);
        const float* sc = (const float*)(wsb + WS_SC);
        const float* bi = (const float*)(wsb + WS_BI);

        int mt = wv / 3, nt = wv % 3;
        int pxc = nt * 16 + (l & 15);
        int bbase = pxc * 896 + ((l >> 4) << 4);
        f32x4 acc = {0.f, 0.f, 0.f, 0.f};
#pragma unroll
        for (int ks = 0; ks < KSTEPS; ++ks) {
            half8 bfr = *(const half8*)(lds + ((bbase + ks * 64) ^ swz));
            half8 afr = *(const half8*)(Ad + ((ks * 3 + mt) * 64 + l) * 8);
            acc = __builtin_amdgcn_mfma_f32_16x16x32_f16(afr, bfr, acc, 0, 0, 0);
        }
        int rowg = (l >> 4) * 4;
#pragma unroll
        for (int r = 0; r < 4; ++r) {
            int o = mt * 16 + rowg + r;
            size_t addr = ((size_t)(n * C + o)) * HW + tile * PXB + pxc;
            float v = fmaf(acc[r], sc[o], bi[o]) + x[addr];
            out[addr] = fmaxf(v, 0.f);
        }
    }
}

// ---------------------------------------------------------------------------
extern "C" void kernel_launch(void* const* d_in, const int* in_sizes, int n_in,
                              void* d_out, int out_size, void* d_ws, size_t ws_size,
                              hipStream_t stream)
{
    const float* x     = (const float*)d_in[0];
    const float* tm_w  = (const float*)d_in[1];
    const float* tm_b  = (const float*)d_in[2];
    const float* tr_w  = (const float*)d_in[3];
    const float* tr_b  = (const float*)d_in[4];
    const float* mk_w  = (const float*)d_in[5];
    const float* mk_b  = (const float*)d_in[6];
    const float* dw    = (const float*)d_in[7];
    const float* gamma = (const float*)d_in[8];
    const float* beta  = (const float*)d_in[9];
    const float* rmean = (const float*)d_in[10];
    const float* rvar  = (const float*)d_in[11];
    float* out = (float*)d_out;
    unsigned char* wsb = (unsigned char*)d_ws;

    hipLaunchKernelGGL(transpose_prep_kernel, dim3(P / 64), dim3(256), 0, stream,
                       x, tm_w, tr_w, mk_w, dw, gamma, beta, rmean, rvar, wsb);
    hipLaunchKernelGGL(fused_kernel, dim3(P / PXB), dim3(576), 0, stream,
                       x, tm_b, tr_b, mk_b, wsb, out);
}